// Round 1
// baseline (2571.877 us; speedup 1.0000x reference)
//
#include <hip/hip_runtime.h>

#define N_ITEMS 20000
#define N_USERS 2048
#define NNZ     4000000

// ---------------- ws layout (bytes, 256-aligned) ----------------
// XT bf16 [N_ITEMS][N_USERS]            : 81,920,000
// csr_col int [NNZ]                     : 16,000,000
// csr_val f32 [NNZ]                     : 16,000,000
// row_ptr int [N_ITEMS+1]               : 80,004 -> 80,128
// cursor  int [N_ITEMS]                 : 80,000 -> 80,128
// cnt     int [N_ITEMS]                 : 80,000 -> 80,128
// total ~114.2 MB
#define OFF_XT      ((size_t)0)
#define OFF_CSRCOL  ((size_t)81920000)
#define OFF_CSRVAL  (OFF_CSRCOL + 16000000)
#define OFF_ROWPTR  (OFF_CSRVAL + 16000000)
#define OFF_CURSOR  (OFF_ROWPTR + 80128)
#define OFF_CNT     (OFF_CURSOR + 80128)

static __device__ __forceinline__ unsigned short f2bf(float f) {
  unsigned u = __float_as_uint(f);
  unsigned r = (u + 0x7fffu + ((u >> 16) & 1u)) >> 16;
  return (unsigned short)r;
}
static __device__ __forceinline__ float bf2f(unsigned short s) {
  return __uint_as_float(((unsigned)s) << 16);
}

// X [N_USERS][N_ITEMS] f32  ->  XT [N_ITEMS][N_USERS] bf16
__global__ __launch_bounds__(256) void transpose_kernel(
    const float* __restrict__ X, unsigned short* __restrict__ XT) {
  __shared__ float tile[64][65];
  int k0 = blockIdx.x * 64;   // item tile
  int u0 = blockIdx.y * 64;   // user tile
  int lane = threadIdx.x & 63;
  int dq = threadIdx.x >> 6;  // 0..3
  #pragma unroll
  for (int m = 0; m < 16; ++m) {
    int u = u0 + dq + 4 * m;
    int k = k0 + lane;
    float v = 0.f;
    if (k < N_ITEMS) v = X[(size_t)u * N_ITEMS + k];
    tile[lane][dq + 4 * m] = v;   // tile[k_local][u_local]
  }
  __syncthreads();
  #pragma unroll
  for (int m = 0; m < 16; ++m) {
    int k = k0 + dq + 4 * m;
    if (k < N_ITEMS)
      XT[(size_t)k * N_USERS + u0 + lane] = f2bf(tile[dq + 4 * m][lane]);
  }
}

__global__ void zero_kernel(int* __restrict__ p, int n) {
  int i = blockIdx.x * blockDim.x + threadIdx.x;
  if (i < n) p[i] = 0;
}

__global__ void count_kernel(const int* __restrict__ rows, int* __restrict__ cnt) {
  int i = blockIdx.x * blockDim.x + threadIdx.x;
  if (i < NNZ) atomicAdd(&cnt[rows[i]], 1);
}

// single-block exclusive scan of cnt[N_ITEMS] -> row_ptr, cursor
__global__ __launch_bounds__(1024) void scan_kernel(
    const int* __restrict__ cnt, int* __restrict__ row_ptr, int* __restrict__ cursor) {
  __shared__ int buf[1024];
  __shared__ int carry;
  int tid = threadIdx.x;
  if (tid == 0) carry = 0;
  __syncthreads();
  for (int base = 0; base < N_ITEMS; base += 1024) {
    int i = base + tid;
    int x = (i < N_ITEMS) ? cnt[i] : 0;
    buf[tid] = x;
    __syncthreads();
    for (int off = 1; off < 1024; off <<= 1) {
      int y = (tid >= off) ? buf[tid - off] : 0;
      __syncthreads();
      buf[tid] += y;
      __syncthreads();
    }
    int incl = buf[tid];
    int excl = incl - x;
    int c = carry;
    if (i < N_ITEMS) { row_ptr[i] = c + excl; cursor[i] = c + excl; }
    __syncthreads();
    if (tid == 1023) carry = c + incl;
    __syncthreads();
  }
  if (tid == 0) row_ptr[N_ITEMS] = carry;
}

__global__ void scatter_kernel(const int* __restrict__ rows, const int* __restrict__ cols,
                               const float* __restrict__ vals, int* __restrict__ cursor,
                               int* __restrict__ csr_col, float* __restrict__ csr_val) {
  int i = blockIdx.x * blockDim.x + threadIdx.x;
  if (i < NNZ) {
    int r = rows[i];
    int pos = atomicAdd(&cursor[r], 1);
    csr_col[pos] = cols[i];
    csr_val[pos] = vals[i];
  }
}

// Out[u,r] = sum_j csr_val[j] * XT[csr_col[j]][u]  for j in row r
// WG: 256 thr = 4 waves; owns 16 rows (r) x 64 users (u). lane = user.
// grid = 1250 r_blocks * 32 u_chunks = 40000. Swizzle: xcd = wg&7 owns
// u_chunks 4*xcd..4*xcd+3; consecutive slots sweep r for one u_chunk so the
// 2.5 MB XT u-slice stays resident in that XCD's 4 MB L2.
__global__ __launch_bounds__(256) void spmm_kernel(
    const int* __restrict__ row_ptr, const int* __restrict__ csr_col,
    const float* __restrict__ csr_val, const unsigned short* __restrict__ xt,
    float* __restrict__ out) {
  __shared__ float tile[16][65];
  int wg = blockIdx.x;
  int xcd = wg & 7;
  int slot = wg >> 3;          // [0, 5000)
  int uloc = slot / 1250;      // [0, 4)
  int rb = slot - uloc * 1250; // [0, 1250)
  int u0 = (xcd * 4 + uloc) * 64;
  int r0 = rb * 16;
  int lane = threadIdx.x & 63;
  int wave = __builtin_amdgcn_readfirstlane((int)(threadIdx.x >> 6));

  const unsigned short* xt_u = xt + u0 + lane;

  for (int rr = 0; rr < 4; ++rr) {
    int r = r0 + wave * 4 + rr;
    int jb = row_ptr[r];
    int je = row_ptr[r + 1];
    float acc0 = 0.f, acc1 = 0.f;
    int j = jb;
    for (; j + 4 <= je; j += 4) {
      int   c0 = csr_col[j + 0]; float v0 = csr_val[j + 0];
      int   c1 = csr_col[j + 1]; float v1 = csr_val[j + 1];
      int   c2 = csr_col[j + 2]; float v2 = csr_val[j + 2];
      int   c3 = csr_col[j + 3]; float v3 = csr_val[j + 3];
      float x0 = bf2f(xt_u[(size_t)c0 * N_USERS]);
      float x1 = bf2f(xt_u[(size_t)c1 * N_USERS]);
      float x2 = bf2f(xt_u[(size_t)c2 * N_USERS]);
      float x3 = bf2f(xt_u[(size_t)c3 * N_USERS]);
      acc0 = fmaf(v0, x0, acc0);
      acc1 = fmaf(v1, x1, acc1);
      acc0 = fmaf(v2, x2, acc0);
      acc1 = fmaf(v3, x3, acc1);
    }
    for (; j < je; ++j) {
      int c = csr_col[j]; float v = csr_val[j];
      acc0 = fmaf(v, bf2f(xt_u[(size_t)c * N_USERS]), acc0);
    }
    tile[wave * 4 + rr][lane] = acc0 + acc1;
  }
  __syncthreads();
  // store [64u x 16r] tile: thread -> (u_local = t>>2, rq = (t&3)*4), float4
  int ul = threadIdx.x >> 2;
  int rq = (threadIdx.x & 3) * 4;
  float4 o;
  o.x = tile[rq + 0][ul];
  o.y = tile[rq + 1][ul];
  o.z = tile[rq + 2][ul];
  o.w = tile[rq + 3][ul];
  *reinterpret_cast<float4*>(&out[(size_t)(u0 + ul) * N_ITEMS + r0 + rq]) = o;
}

extern "C" void kernel_launch(void* const* d_in, const int* in_sizes, int n_in,
                              void* d_out, int out_size, void* d_ws, size_t ws_size,
                              hipStream_t stream) {
  const float* X      = (const float*)d_in[0];
  const float* S_vals = (const float*)d_in[1];
  const int*   S_rows = (const int*)d_in[2];
  const int*   S_cols = (const int*)d_in[3];
  float* out = (float*)d_out;

  char* ws = (char*)d_ws;
  unsigned short* XT  = (unsigned short*)(ws + OFF_XT);
  int*   csr_col      = (int*)(ws + OFF_CSRCOL);
  float* csr_val      = (float*)(ws + OFF_CSRVAL);
  int*   row_ptr      = (int*)(ws + OFF_ROWPTR);
  int*   cursor       = (int*)(ws + OFF_CURSOR);
  int*   cnt          = (int*)(ws + OFF_CNT);

  // 1) transpose X -> XT (bf16)
  transpose_kernel<<<dim3((N_ITEMS + 63) / 64, N_USERS / 64), 256, 0, stream>>>(X, XT);
  // 2) CSR build
  zero_kernel<<<(N_ITEMS + 255) / 256, 256, 0, stream>>>(cnt, N_ITEMS);
  count_kernel<<<NNZ / 256, 256, 0, stream>>>(S_rows, cnt);
  scan_kernel<<<1, 1024, 0, stream>>>(cnt, row_ptr, cursor);
  scatter_kernel<<<NNZ / 256, 256, 0, stream>>>(S_rows, S_cols, S_vals, cursor,
                                                csr_col, csr_val);
  // 3) SpMM
  spmm_kernel<<<1250 * 32, 256, 0, stream>>>(row_ptr, csr_col, csr_val, XT, out);
}

// Round 2
// 1911.304 us; speedup vs baseline: 1.3456x; 1.3456x over previous
//
#include <hip/hip_runtime.h>

#define N_ITEMS 20000
#define N_USERS 2048
#define NNZ     4000000

// ---------------- ws layout (bytes) ----------------
// XT bf16 [N_ITEMS][N_USERS]            : 81,920,000
// csr_pk u32 [NNZ]  (u16 col | bf16 val): 16,000,000
// row_ptr int [N_ITEMS+1]               : 80,128
// cursor  int [N_ITEMS]                 : 80,128
// cnt     int [N_ITEMS]                 : 80,128
#define OFF_XT      ((size_t)0)
#define OFF_CSRPK   ((size_t)81920000)
#define OFF_ROWPTR  (OFF_CSRPK + 16000000)
#define OFF_CURSOR  (OFF_ROWPTR + 80128)
#define OFF_CNT     (OFF_CURSOR + 80128)

static __device__ __forceinline__ unsigned short f2bf(float f) {
  unsigned u = __float_as_uint(f);
  unsigned r = (u + 0x7fffu + ((u >> 16) & 1u)) >> 16;
  return (unsigned short)r;
}
static __device__ __forceinline__ float bf2f(unsigned short s) {
  return __uint_as_float(((unsigned)s) << 16);
}

// X [N_USERS][N_ITEMS] f32  ->  XT [N_ITEMS][N_USERS] bf16
__global__ __launch_bounds__(256) void transpose_kernel(
    const float* __restrict__ X, unsigned short* __restrict__ XT) {
  __shared__ float tile[64][65];
  int k0 = blockIdx.x * 64;   // item tile
  int u0 = blockIdx.y * 64;   // user tile
  int lane = threadIdx.x & 63;
  int dq = threadIdx.x >> 6;  // 0..3
  #pragma unroll
  for (int m = 0; m < 16; ++m) {
    int u = u0 + dq + 4 * m;
    int k = k0 + lane;
    float v = 0.f;
    if (k < N_ITEMS) v = X[(size_t)u * N_ITEMS + k];
    tile[lane][dq + 4 * m] = v;   // tile[k_local][u_local]
  }
  __syncthreads();
  #pragma unroll
  for (int m = 0; m < 16; ++m) {
    int k = k0 + dq + 4 * m;
    if (k < N_ITEMS)
      XT[(size_t)k * N_USERS + u0 + lane] = f2bf(tile[dq + 4 * m][lane]);
  }
}

__global__ void zero_kernel(int* __restrict__ p, int n) {
  int i = blockIdx.x * blockDim.x + threadIdx.x;
  if (i < n) p[i] = 0;
}

__global__ void count_kernel(const int* __restrict__ rows, int* __restrict__ cnt) {
  int i = blockIdx.x * blockDim.x + threadIdx.x;
  if (i < NNZ) atomicAdd(&cnt[rows[i]], 1);
}

// single-block exclusive scan of cnt[N_ITEMS] -> row_ptr, cursor
__global__ __launch_bounds__(1024) void scan_kernel(
    const int* __restrict__ cnt, int* __restrict__ row_ptr, int* __restrict__ cursor) {
  __shared__ int buf[1024];
  __shared__ int carry;
  int tid = threadIdx.x;
  if (tid == 0) carry = 0;
  __syncthreads();
  for (int base = 0; base < N_ITEMS; base += 1024) {
    int i = base + tid;
    int x = (i < N_ITEMS) ? cnt[i] : 0;
    buf[tid] = x;
    __syncthreads();
    for (int off = 1; off < 1024; off <<= 1) {
      int y = (tid >= off) ? buf[tid - off] : 0;
      __syncthreads();
      buf[tid] += y;
      __syncthreads();
    }
    int incl = buf[tid];
    int excl = incl - x;
    int c = carry;
    if (i < N_ITEMS) { row_ptr[i] = c + excl; cursor[i] = c + excl; }
    __syncthreads();
    if (tid == 1023) carry = c + incl;
    __syncthreads();
  }
  if (tid == 0) row_ptr[N_ITEMS] = carry;
}

__global__ void scatter_kernel(const int* __restrict__ rows, const int* __restrict__ cols,
                               const float* __restrict__ vals, int* __restrict__ cursor,
                               unsigned* __restrict__ csr_pk) {
  int i = blockIdx.x * blockDim.x + threadIdx.x;
  if (i < NNZ) {
    int r = rows[i];
    int pos = atomicAdd(&cursor[r], 1);
    csr_pk[pos] = (unsigned)cols[i] | ((unsigned)f2bf(vals[i]) << 16);
  }
}

// Out[u,r] = sum_j val(j) * XT[col(j)][u]  for j in row r
// WG: 256 thr = 4 waves; owns 16 rows (r) x 64 users (u). lane = user.
// grid = 1250 r_blocks * 32 u_chunks. xcd = wg&7 owns u_chunks 4*xcd..4*xcd+3;
// consecutive slots sweep r for one u_chunk -> 2.56 MB XT u-slice L2-resident.
__global__ __launch_bounds__(256) void spmm_kernel(
    const int* __restrict__ row_ptr, const unsigned* __restrict__ csr_pk,
    const unsigned short* __restrict__ xt, float* __restrict__ out) {
  __shared__ float tile[16][65];
  int wg = blockIdx.x;
  int xcd = wg & 7;
  int slot = wg >> 3;          // [0, 5000)
  int uloc = slot / 1250;      // [0, 4)
  int rb = slot - uloc * 1250; // [0, 1250)
  int u0 = (xcd * 4 + uloc) * 64;
  int r0 = rb * 16;
  int lane = threadIdx.x & 63;
  int wave = __builtin_amdgcn_readfirstlane((int)(threadIdx.x >> 6));

  const unsigned short* xt_u = xt + u0 + lane;

  for (int rr = 0; rr < 4; ++rr) {
    int r = r0 + wave * 4 + rr;
    int jb = row_ptr[r];
    int je = row_ptr[r + 1];
    float acc[4] = {0.f, 0.f, 0.f, 0.f};
    int j = jb;
    // 8-deep: 8 uniform csr loads, 8 independent gathers in flight, then FMAs
    for (; j + 8 <= je; j += 8) {
      unsigned e[8];
      #pragma unroll
      for (int k = 0; k < 8; ++k) e[k] = csr_pk[j + k];
      float x[8];
      #pragma unroll
      for (int k = 0; k < 8; ++k)
        x[k] = bf2f(xt_u[(unsigned)((e[k] & 0xffffu) << 11)]);
      #pragma unroll
      for (int k = 0; k < 8; ++k)
        acc[k & 3] = fmaf(bf2f((unsigned short)(e[k] >> 16)), x[k], acc[k & 3]);
    }
    for (; j < je; ++j) {
      unsigned e = csr_pk[j];
      acc[0] = fmaf(bf2f((unsigned short)(e >> 16)),
                    bf2f(xt_u[(unsigned)((e & 0xffffu) << 11)]), acc[0]);
    }
    tile[wave * 4 + rr][lane] = (acc[0] + acc[1]) + (acc[2] + acc[3]);
  }
  __syncthreads();
  // store [64u x 16r] tile: thread -> (u_local = t>>2, rq = (t&3)*4), float4
  int ul = threadIdx.x >> 2;
  int rq = (threadIdx.x & 3) * 4;
  float4 o;
  o.x = tile[rq + 0][ul];
  o.y = tile[rq + 1][ul];
  o.z = tile[rq + 2][ul];
  o.w = tile[rq + 3][ul];
  *reinterpret_cast<float4*>(&out[(size_t)(u0 + ul) * N_ITEMS + r0 + rq]) = o;
}

extern "C" void kernel_launch(void* const* d_in, const int* in_sizes, int n_in,
                              void* d_out, int out_size, void* d_ws, size_t ws_size,
                              hipStream_t stream) {
  const float* X      = (const float*)d_in[0];
  const float* S_vals = (const float*)d_in[1];
  const int*   S_rows = (const int*)d_in[2];
  const int*   S_cols = (const int*)d_in[3];
  float* out = (float*)d_out;

  char* ws = (char*)d_ws;
  unsigned short* XT  = (unsigned short*)(ws + OFF_XT);
  unsigned* csr_pk    = (unsigned*)(ws + OFF_CSRPK);
  int*   row_ptr      = (int*)(ws + OFF_ROWPTR);
  int*   cursor       = (int*)(ws + OFF_CURSOR);
  int*   cnt          = (int*)(ws + OFF_CNT);

  // 1) transpose X -> XT (bf16)
  transpose_kernel<<<dim3((N_ITEMS + 63) / 64, N_USERS / 64), 256, 0, stream>>>(X, XT);
  // 2) CSR build (packed 4B entries)
  zero_kernel<<<(N_ITEMS + 255) / 256, 256, 0, stream>>>(cnt, N_ITEMS);
  count_kernel<<<NNZ / 256, 256, 0, stream>>>(S_rows, cnt);
  scan_kernel<<<1, 1024, 0, stream>>>(cnt, row_ptr, cursor);
  scatter_kernel<<<NNZ / 256, 256, 0, stream>>>(S_rows, S_cols, S_vals, cursor, csr_pk);
  // 3) SpMM
  spmm_kernel<<<1250 * 32, 256, 0, stream>>>(row_ptr, csr_pk, XT, out);
}